// Round 1
// baseline (504.261 us; speedup 1.0000x reference)
//
#include <hip/hip_runtime.h>

#define NN 50000
#define NE 800000
#define DD 128
#define NL 3
#define ELLW 96

// ---------------- ELL build: one atomic per edge ----------------
__global__ __launch_bounds__(256) void build_ell_k(const int* __restrict__ ei,
                                                   int* __restrict__ cnt,
                                                   int* __restrict__ ell) {
  int e = blockIdx.x * 256 + threadIdx.x;
  if (e >= NE) return;
  int s = ei[e];        // src
  int d = ei[NE + e];   // dst
  int pos = atomicAdd(&cnt[d], 1);
  if (pos < ELLW) ell[(size_t)d * ELLW + pos] = s;
}

// ---------------- aggregation: Z = (1+eps)*X + sum_{j in N(i)} X_j ----------------
// 64 threads per node (float2 each -> 512B coalesced row reads), 4 nodes/block.
__global__ __launch_bounds__(256) void aggregate_k(const float* __restrict__ X,
                                                   const int* __restrict__ cnt,
                                                   const int* __restrict__ ell,
                                                   const float* __restrict__ eps,
                                                   int layer,
                                                   float* __restrict__ Z) {
  int node = blockIdx.x * 4 + (threadIdx.x >> 6);
  if (node >= NN) return;
  int c = threadIdx.x & 63;
  int k = cnt[node]; if (k > ELLW) k = ELLW;
  const int* el = ell + (size_t)node * ELLW;
  const float2* X2 = (const float2*)X;
  float2 acc = make_float2(0.f, 0.f);
  for (int j = 0; j < k; ++j) {
    int s = el[j];  // wave-uniform
    float2 v = X2[(size_t)s * 64 + c];
    acc.x += v.x; acc.y += v.y;
  }
  float e1 = 1.0f + eps[layer];
  float2 xv = X2[(size_t)node * 64 + c];
  float2 z = make_float2(fmaf(e1, xv.x, acc.x), fmaf(e1, xv.y, acc.y));
  ((float2*)Z)[(size_t)node * 64 + c] = z;
}

// ---------------- fp32 tiled GEMM: out = act(A @ W + b) [+ resid] ----------------
// 64x64 tile, 256 threads, 4x4 register blocking, K=128 in two LDS-staged halves.
template<bool RELU, bool RESID>
__global__ __launch_bounds__(256) void gemm_k(const float* __restrict__ A,
                                              const float* __restrict__ W,
                                              const float* __restrict__ bias,
                                              const float* __restrict__ resid,
                                              float* __restrict__ out, int M) {
  __shared__ float As[64][68];   // pad 68 keeps 16B alignment, spreads banks
  __shared__ float Bs[64][64];
  const int tid = threadIdx.x;
  const int tc = tid & 15, tr = tid >> 4;
  const int r0 = tr * 4, c0 = tc * 4;
  const int brow = blockIdx.x * 64;
  const int bcol = blockIdx.y * 64;
  float acc[4][4] = {};

  for (int kh = 0; kh < 2; ++kh) {
    const int k0 = kh * 64;
    // A tile: 64 rows x 64 k  (1024 float4, 4 per thread), guarded rows
#pragma unroll
    for (int it = 0; it < 4; ++it) {
      int idx = tid + it * 256;
      int r = idx >> 4;
      int kq = idx & 15;
      float4 v = make_float4(0.f, 0.f, 0.f, 0.f);
      int grow = brow + r;
      if (grow < M) v = *(const float4*)(A + (size_t)grow * DD + k0 + kq * 4);
      *(float4*)&As[r][kq * 4] = v;
    }
    // B tile: W[k0+kk][bcol+c], 64x64
#pragma unroll
    for (int it = 0; it < 4; ++it) {
      int idx = tid + it * 256;
      int kk = idx >> 4;
      int cq = idx & 15;
      float4 v = *(const float4*)(W + (size_t)(k0 + kk) * DD + bcol + cq * 4);
      *(float4*)&Bs[kk][cq * 4] = v;
    }
    __syncthreads();
    union F4 { float4 v; float f[4]; };
#pragma unroll
    for (int k4 = 0; k4 < 16; ++k4) {
      F4 a[4], bfr[4];
#pragma unroll
      for (int i = 0; i < 4; ++i) a[i].v = *(const float4*)&As[r0 + i][k4 * 4];
#pragma unroll
      for (int u = 0; u < 4; ++u) bfr[u].v = *(const float4*)&Bs[k4 * 4 + u][c0];
#pragma unroll
      for (int i = 0; i < 4; ++i)
#pragma unroll
        for (int u = 0; u < 4; ++u)
#pragma unroll
          for (int j = 0; j < 4; ++j)
            acc[i][j] = fmaf(a[i].f[u], bfr[u].f[j], acc[i][j]);
    }
    __syncthreads();
  }

  float4 bv = *(const float4*)(bias + bcol + c0);
#pragma unroll
  for (int i = 0; i < 4; ++i) {
    int grow = brow + r0 + i;
    if (grow >= M) continue;
    float4 v;
    v.x = acc[i][0] + bv.x; v.y = acc[i][1] + bv.y;
    v.z = acc[i][2] + bv.z; v.w = acc[i][3] + bv.w;
    if (RELU) {
      v.x = fmaxf(v.x, 0.f); v.y = fmaxf(v.y, 0.f);
      v.z = fmaxf(v.z, 0.f); v.w = fmaxf(v.w, 0.f);
    }
    if (RESID) {
      float4 rv = *(const float4*)(resid + (size_t)grow * DD + bcol + c0);
      v.x += rv.x; v.y += rv.y; v.z += rv.z; v.w += rv.w;
    }
    *(float4*)(out + (size_t)grow * DD + bcol + c0) = v;
  }
}

extern "C" void kernel_launch(void* const* d_in, const int* in_sizes, int n_in,
                              void* d_out, int out_size, void* d_ws, size_t ws_size,
                              hipStream_t stream) {
  const float* X   = (const float*)d_in[0];
  const int*   ei  = (const int*)d_in[1];
  const float* eps = (const float*)d_in[2];
  const float* W1  = (const float*)d_in[3];
  const float* b1  = (const float*)d_in[4];
  const float* W2  = (const float*)d_in[5];
  const float* b2  = (const float*)d_in[6];
  float* Xout = (float*)d_out;

  char* ws = (char*)d_ws;
  size_t cnt_bytes = 256 * (((size_t)NN * 4 + 255) / 256);
  int* cnt = (int*)ws;
  int* ell = (int*)(ws + cnt_bytes);
  size_t z_off = cnt_bytes + (size_t)NN * ELLW * 4;
  z_off = 256 * ((z_off + 255) / 256);
  float* Z = (float*)(ws + z_off);
  float* H = (float*)(ws + z_off + (size_t)NN * DD * 4);

  hipMemsetAsync(cnt, 0, NN * 4, stream);
  build_ell_k<<<(NE + 255) / 256, 256, 0, stream>>>(ei, cnt, ell);

  dim3 ggrid((NN + 63) / 64, 2);
  for (int l = 0; l < NL; ++l) {
    const float* Xcur = (l == 0) ? X : Xout;
    aggregate_k<<<(NN + 3) / 4, 256, 0, stream>>>(Xcur, cnt, ell, eps, l, Z);
    gemm_k<true,  false><<<ggrid, 256, 0, stream>>>(Z, W1 + (size_t)l * DD * DD,
                                                    b1 + (size_t)l * DD, nullptr, H, NN);
    gemm_k<false, true ><<<ggrid, 256, 0, stream>>>(H, W2 + (size_t)l * DD * DD,
                                                    b2 + (size_t)l * DD, Xcur, Xout, NN);
  }
}

// Round 3
// 351.698 us; speedup vs baseline: 1.4338x; 1.4338x over previous
//
#include <hip/hip_runtime.h>

#define NN 50000
#define NE 800000
#define DD 128
#define NL 3
#define ELLW 96
#define MT_TOTAL (NN / 16)   // 3125 m-tiles of 16 rows

typedef short bf16x8 __attribute__((ext_vector_type(8)));
typedef float f32x4 __attribute__((ext_vector_type(4)));

__device__ __forceinline__ unsigned short f2bf(float x) {
  unsigned u = __float_as_uint(x);
  u += 0x7FFFu + ((u >> 16) & 1u);          // RTN-even
  return (unsigned short)(u >> 16);
}
__device__ __forceinline__ float bf2f(unsigned short h) {
  return __uint_as_float(((unsigned)h) << 16);
}

// ---------------- ELL build: one atomic per edge ----------------
__global__ __launch_bounds__(256) void build_ell_k(const int* __restrict__ ei,
                                                   int* __restrict__ cnt,
                                                   int* __restrict__ ell) {
  int e = blockIdx.x * 256 + threadIdx.x;
  if (e >= NE) return;
  int s = ei[e];        // src
  int d = ei[NE + e];   // dst
  int pos = atomicAdd(&cnt[d], 1);
  if (pos < ELLW) ell[(size_t)d * ELLW + pos] = s;
}

// ---------------- one-time W fragment pack: fp32 -> bf16 hi/lo, MFMA B-frag order ----
// Per matrix: [hi plane 16384][lo plane 16384]; frag offset ((nt*4+ks)*64 + lane)*8,
// element (k = ks*32 + (lane>>4)*8 + i, col = nt*16 + (lane&15)).
__global__ __launch_bounds__(256) void pack_w_k(const float* __restrict__ W1,
                                                const float* __restrict__ W2,
                                                unsigned short* __restrict__ Wp) {
  int t = blockIdx.x * 256 + threadIdx.x;
  if (t >= 6 * 2048) return;
  int m = t >> 11;
  int rem = t & 2047;              // (nt*4+ks)*64 + lane
  int l = rem & 63;
  int ntks = rem >> 6;             // 0..31
  int ks = ntks & 3, nt = ntks >> 2;
  const float* W = (m < 3) ? (W1 + (size_t)m * DD * DD) : (W2 + (size_t)(m - 3) * DD * DD);
  int col = nt * 16 + (l & 15);
  int k0 = ks * 32 + (l >> 4) * 8;
  unsigned short* hi = Wp + (size_t)m * 2 * DD * DD + (size_t)rem * 8;
  unsigned short* lo = hi + DD * DD;
#pragma unroll
  for (int i = 0; i < 8; ++i) {
    float w = W[(size_t)(k0 + i) * DD + col];
    unsigned short h = f2bf(w);
    hi[i] = h;
    lo[i] = f2bf(w - bf2f(h));
  }
}

// ---------------- aggregation: Z = (1+eps)*X + sum_{j in N(i)} X_j -> bf16 hi/lo ----
// 32 lanes/node, float4/lane; indices prefetched 4-at-a-time (wave-uniform int4).
__global__ __launch_bounds__(256) void aggregate_k(const float* __restrict__ X,
                                                   const int* __restrict__ cnt,
                                                   const int* __restrict__ ell,
                                                   const float* __restrict__ eps,
                                                   int layer,
                                                   unsigned short* __restrict__ Zhi,
                                                   unsigned short* __restrict__ Zlo) {
  int node = blockIdx.x * 8 + (threadIdx.x >> 5);
  if (node >= NN) return;
  int lane = threadIdx.x & 31;
  int k = cnt[node]; if (k > ELLW) k = ELLW;
  const int* el = ell + (size_t)node * ELLW;
  const int4* el4 = (const int4*)el;
  const float4* X4 = (const float4*)X;
  float4 acc = make_float4(0.f, 0.f, 0.f, 0.f);
  int nfull = k >> 2;
  int4 nxt;
  if (nfull) nxt = el4[0];
  for (int t = 0; t < nfull; ++t) {
    int4 cur = nxt;
    if (t + 1 < nfull) nxt = el4[t + 1];
    float4 v0 = X4[(size_t)cur.x * 32 + lane];
    float4 v1 = X4[(size_t)cur.y * 32 + lane];
    float4 v2 = X4[(size_t)cur.z * 32 + lane];
    float4 v3 = X4[(size_t)cur.w * 32 + lane];
    acc.x += (v0.x + v1.x) + (v2.x + v3.x);
    acc.y += (v0.y + v1.y) + (v2.y + v3.y);
    acc.z += (v0.z + v1.z) + (v2.z + v3.z);
    acc.w += (v0.w + v1.w) + (v2.w + v3.w);
  }
  for (int j = nfull * 4; j < k; ++j) {
    float4 v = X4[(size_t)el[j] * 32 + lane];
    acc.x += v.x; acc.y += v.y; acc.z += v.z; acc.w += v.w;
  }
  float e1 = 1.0f + eps[layer];
  float4 xv = X4[(size_t)node * 32 + lane];
  float z[4];
  z[0] = fmaf(e1, xv.x, acc.x);
  z[1] = fmaf(e1, xv.y, acc.y);
  z[2] = fmaf(e1, xv.z, acc.z);
  z[3] = fmaf(e1, xv.w, acc.w);
  unsigned short h[4], lo[4];
#pragma unroll
  for (int i = 0; i < 4; ++i) {
    h[i] = f2bf(z[i]);
    lo[i] = f2bf(z[i] - bf2f(h[i]));
  }
  size_t base = (size_t)node * DD + lane * 4;
  *(ushort4*)(Zhi + base) = make_ushort4(h[0], h[1], h[2], h[3]);
  *(ushort4*)(Zlo + base) = make_ushort4(lo[0], lo[1], lo[2], lo[3]);
}

// ---------------- LDS-free split-bf16 MFMA GEMM ----------------
// 1 wave = 16 rows x 128 cols. A from bf16 hi/lo planes (row-major), W from packed frags.
// MODE 0: out = ReLU(A@W + b) -> bf16 hi/lo planes.  MODE 1: out = A@W + b + resid -> fp32.
template<int MODE>
__global__ __launch_bounds__(256) void mfma_gemm_k(const unsigned short* __restrict__ Ahi,
                                                   const unsigned short* __restrict__ Alo,
                                                   const unsigned short* __restrict__ Wp,
                                                   const float* __restrict__ bias,
                                                   const float* __restrict__ resid,
                                                   float* __restrict__ outF,
                                                   unsigned short* __restrict__ outHi,
                                                   unsigned short* __restrict__ outLo) {
  int mt = blockIdx.x * 4 + (threadIdx.x >> 6);
  if (mt >= MT_TOTAL) return;
  int l = threadIdx.x & 63;
  int arow = mt * 16 + (l & 15);
  int g = l >> 4;
  f32x4 acc[8];
#pragma unroll
  for (int nt = 0; nt < 8; ++nt) acc[nt] = (f32x4){0.f, 0.f, 0.f, 0.f};
  const unsigned short* Whi = Wp;
  const unsigned short* Wlo = Wp + DD * DD;
#pragma unroll
  for (int ks = 0; ks < 4; ++ks) {
    int k0 = ks * 32 + g * 8;
    bf16x8 ahi = *(const bf16x8*)(Ahi + (size_t)arow * DD + k0);
    bf16x8 alo = *(const bf16x8*)(Alo + (size_t)arow * DD + k0);
#pragma unroll
    for (int nt = 0; nt < 8; ++nt) {
      size_t off = ((size_t)(nt * 4 + ks) * 64 + l) * 8;
      bf16x8 bhi = *(const bf16x8*)(Whi + off);
      bf16x8 blo = *(const bf16x8*)(Wlo + off);
      acc[nt] = __builtin_amdgcn_mfma_f32_16x16x32_bf16(ahi, bhi, acc[nt], 0, 0, 0);
      acc[nt] = __builtin_amdgcn_mfma_f32_16x16x32_bf16(ahi, blo, acc[nt], 0, 0, 0);
      acc[nt] = __builtin_amdgcn_mfma_f32_16x16x32_bf16(alo, bhi, acc[nt], 0, 0, 0);
    }
  }
  int orow0 = mt * 16 + g * 4;   // C/D: row = (lane>>4)*4 + reg, col = lane&15
#pragma unroll
  for (int nt = 0; nt < 8; ++nt) {
    int col = nt * 16 + (l & 15);
    float bv = bias[col];
#pragma unroll
    for (int r = 0; r < 4; ++r) {
      int orow = orow0 + r;
      float v = acc[nt][r] + bv;
      if (MODE == 0) {
        v = fmaxf(v, 0.f);
        unsigned short h = f2bf(v);
        outHi[(size_t)orow * DD + col] = h;
        outLo[(size_t)orow * DD + col] = f2bf(v - bf2f(h));
      } else {
        v += resid[(size_t)orow * DD + col];
        outF[(size_t)orow * DD + col] = v;
      }
    }
  }
}

extern "C" void kernel_launch(void* const* d_in, const int* in_sizes, int n_in,
                              void* d_out, int out_size, void* d_ws, size_t ws_size,
                              hipStream_t stream) {
  const float* X   = (const float*)d_in[0];
  const int*   ei  = (const int*)d_in[1];
  const float* eps = (const float*)d_in[2];
  const float* W1  = (const float*)d_in[3];
  const float* b1  = (const float*)d_in[4];
  const float* W2  = (const float*)d_in[5];
  const float* b2  = (const float*)d_in[6];
  float* Xout = (float*)d_out;

  char* ws = (char*)d_ws;
  size_t off = 0;
  int* cnt = (int*)(ws + off); off += 256 * (((size_t)NN * 4 + 255) / 256);
  int* ell = (int*)(ws + off); off += (size_t)NN * ELLW * 4;           // 384B rows: 16B aligned
  unsigned short* Zhi = (unsigned short*)(ws + off); off += (size_t)NN * DD * 2;
  unsigned short* Zlo = (unsigned short*)(ws + off); off += (size_t)NN * DD * 2;
  unsigned short* Hhi = (unsigned short*)(ws + off); off += (size_t)NN * DD * 2;
  unsigned short* Hlo = (unsigned short*)(ws + off); off += (size_t)NN * DD * 2;
  unsigned short* Wp  = (unsigned short*)(ws + off); off += (size_t)6 * 2 * DD * DD * 2;

  hipMemsetAsync(cnt, 0, NN * 4, stream);
  build_ell_k<<<(NE + 255) / 256, 256, 0, stream>>>(ei, cnt, ell);
  pack_w_k<<<(6 * 2048 + 255) / 256, 256, 0, stream>>>(W1, W2, Wp);

  const int ggrid = (MT_TOTAL + 3) / 4;  // 782 blocks, 4 waves each
  for (int l = 0; l < NL; ++l) {
    const float* Xcur = (l == 0) ? X : Xout;
    aggregate_k<<<(NN + 7) / 8, 256, 0, stream>>>(Xcur, cnt, ell, eps, l, Zhi, Zlo);
    mfma_gemm_k<0><<<ggrid, 256, 0, stream>>>(Zhi, Zlo, Wp + (size_t)l * 2 * DD * DD,
                                              b1 + (size_t)l * DD, nullptr, nullptr, Hhi, Hlo);
    mfma_gemm_k<1><<<ggrid, 256, 0, stream>>>(Hhi, Hlo, Wp + (size_t)(3 + l) * 2 * DD * DD,
                                              b2 + (size_t)l * DD, Xcur, Xout, nullptr, nullptr);
  }
}

// Round 4
// 222.568 us; speedup vs baseline: 2.2656x; 1.5802x over previous
//
#include <hip/hip_runtime.h>

#define NN 50000
#define NE 800000
#define DD 128
#define NL 3
#define ELLW 96
#define MT_TOTAL (NN / 16)   // 3125 wave-tiles of 16 rows

typedef short bf16x8 __attribute__((ext_vector_type(8)));
typedef float f32x4 __attribute__((ext_vector_type(4)));
typedef _Float16 half8 __attribute__((ext_vector_type(8)));

__device__ __forceinline__ unsigned short f2bf(float x) {
  unsigned u = __float_as_uint(x);
  u += 0x7FFFu + ((u >> 16) & 1u);          // RTN-even
  return (unsigned short)(u >> 16);
}
__device__ __forceinline__ float bf2f(unsigned short h) {
  return __uint_as_float(((unsigned)h) << 16);
}
__device__ __forceinline__ void cvt8(float4 z0, float4 z1, bf16x8* hi, bf16x8* lo) {
  float zz[8] = {z0.x, z0.y, z0.z, z0.w, z1.x, z1.y, z1.z, z1.w};
#pragma unroll
  for (int i = 0; i < 8; ++i) {
    unsigned short h = f2bf(zz[i]);
    (*hi)[i] = (short)h;
    (*lo)[i] = (short)f2bf(zz[i] - bf2f(h));
  }
}

// ---------------- ELL build: one atomic per edge ----------------
__global__ __launch_bounds__(256) void build_ell_k(const int* __restrict__ ei,
                                                   int* __restrict__ cnt,
                                                   int* __restrict__ ell) {
  int e = blockIdx.x * 256 + threadIdx.x;
  if (e >= NE) return;
  int s = ei[e];        // src
  int d = ei[NE + e];   // dst
  int pos = atomicAdd(&cnt[d], 1);
  if (pos < ELLW) ell[(size_t)d * ELLW + pos] = s;
}

// ---------------- one-time W fragment pack: fp32 -> bf16 hi/lo, MFMA B-frag order ----
// Per matrix: [hi plane 16384][lo plane 16384]; frag offset ((nt*4+ks)*64 + lane)*8,
// element (k = ks*32 + (lane>>4)*8 + i, col = nt*16 + (lane&15)).
__global__ __launch_bounds__(256) void pack_w_k(const float* __restrict__ W1,
                                                const float* __restrict__ W2,
                                                unsigned short* __restrict__ Wp) {
  int t = blockIdx.x * 256 + threadIdx.x;
  if (t >= 6 * 2048) return;
  int m = t >> 11;
  int rem = t & 2047;              // (nt*4+ks)*64 + lane
  int l = rem & 63;
  int ntks = rem >> 6;             // 0..31
  int ks = ntks & 3, nt = ntks >> 2;
  const float* W = (m < 3) ? (W1 + (size_t)m * DD * DD) : (W2 + (size_t)(m - 3) * DD * DD);
  int col = nt * 16 + (l & 15);
  int k0 = ks * 32 + (l >> 4) * 8;
  unsigned short* hi = Wp + (size_t)m * 2 * DD * DD + (size_t)rem * 8;
  unsigned short* lo = hi + DD * DD;
#pragma unroll
  for (int i = 0; i < 8; ++i) {
    float w = W[(size_t)(k0 + i) * DD + col];
    unsigned short h = f2bf(w);
    hi[i] = h;
    lo[i] = f2bf(w - bf2f(h));
  }
}

// ---------------- fp16 mirror init ----------------
__global__ __launch_bounds__(256) void xh_init_k(const float* __restrict__ X,
                                                 _Float16* __restrict__ Xh) {
  int t = blockIdx.x * 256 + threadIdx.x;
  if (t >= NN * DD / 8) return;
  const float4* p = (const float4*)X + (size_t)t * 2;
  float4 a = p[0], b = p[1];
  half8 h;
  h[0] = (_Float16)a.x; h[1] = (_Float16)a.y; h[2] = (_Float16)a.z; h[3] = (_Float16)a.w;
  h[4] = (_Float16)b.x; h[5] = (_Float16)b.y; h[6] = (_Float16)b.z; h[7] = (_Float16)b.w;
  *(half8*)(Xh + (size_t)t * 8) = h;
}

// ---------------- fused layer: aggregate -> GEMM1+ReLU -> GEMM2+resid ----------------
// 256 threads = 4 waves; each wave owns a 16-row tile (16x132 fp32 in LDS, reused Z->H).
// Gather: 16 lanes/node (fp16 rows), 4 nodes concurrently, 4 passes.
// GEMMs: split-bf16 3-MFMA, A-frags converted from LDS fp32, B-frags from packed Wp.
template<int WRITE_H>
__global__ __launch_bounds__(256) void fused_layer_k(
    const float* __restrict__ Xf_in, const _Float16* __restrict__ Xh_in,
    const int* __restrict__ cnt, const int* __restrict__ ell,
    const float* __restrict__ eps, int layer,
    const unsigned short* __restrict__ Wp1, const float* __restrict__ b1,
    const unsigned short* __restrict__ Wp2, const float* __restrict__ b2,
    float* __restrict__ Xf_out, _Float16* __restrict__ Xh_out)
{
  __shared__ float tile[4][16 * 132];   // pitch 132: frag reads 2-way bank-aliased (free)
  const int w = threadIdx.x >> 6, l = threadIdx.x & 63;
  const int mt = blockIdx.x * 4 + w;
  const bool active = (mt < MT_TOTAL);
  const int c = l & 15, grp = l >> 4;
  float* my = tile[w];

  // ---- phase A: aggregation ----
  if (active) {
    const float e1 = 1.0f + eps[layer];
    for (int pass = 0; pass < 4; ++pass) {
      int nl = pass * 4 + grp;
      int node = mt * 16 + nl;
      int deg = cnt[node]; deg = deg > ELLW ? ELLW : deg;
      const int* el = ell + (size_t)node * ELLW;
      const int4* el4 = (const int4*)el;
      float acc[8];
      {
        const float* xr = Xf_in + (size_t)node * DD + c * 8;
        float4 a0 = *(const float4*)xr, a1 = *(const float4*)(xr + 4);
        acc[0] = e1 * a0.x; acc[1] = e1 * a0.y; acc[2] = e1 * a0.z; acc[3] = e1 * a0.w;
        acc[4] = e1 * a1.x; acc[5] = e1 * a1.y; acc[6] = e1 * a1.z; acc[7] = e1 * a1.w;
      }
      int nf = deg >> 2;
      int4 nxt;
      if (nf) nxt = el4[0];
      for (int t = 0; t < nf; ++t) {
        int4 cur = nxt;
        if (t + 1 < nf) nxt = el4[t + 1];
        half8 v0 = *(const half8*)(Xh_in + (size_t)cur.x * DD + c * 8);
        half8 v1 = *(const half8*)(Xh_in + (size_t)cur.y * DD + c * 8);
        half8 v2 = *(const half8*)(Xh_in + (size_t)cur.z * DD + c * 8);
        half8 v3 = *(const half8*)(Xh_in + (size_t)cur.w * DD + c * 8);
#pragma unroll
        for (int i = 0; i < 8; ++i)
          acc[i] += ((float)v0[i] + (float)v1[i]) + ((float)v2[i] + (float)v3[i]);
      }
      for (int j = nf * 4; j < deg; ++j) {
        half8 v = *(const half8*)(Xh_in + (size_t)el[j] * DD + c * 8);
#pragma unroll
        for (int i = 0; i < 8; ++i) acc[i] += (float)v[i];
      }
      float* dst = my + nl * 132 + c * 8;
      *(float4*)dst = make_float4(acc[0], acc[1], acc[2], acc[3]);
      *(float4*)(dst + 4) = make_float4(acc[4], acc[5], acc[6], acc[7]);
    }
  }
  __syncthreads();

  // ---- phase B: GEMM1 (Z @ W1), ReLU, H -> LDS ----
  f32x4 acc1[8];
#pragma unroll
  for (int nt = 0; nt < 8; ++nt) acc1[nt] = (f32x4){0.f, 0.f, 0.f, 0.f};
  if (active) {
    const float* arow = my + (l & 15) * 132;
    const unsigned short* Whi = Wp1;
    const unsigned short* Wlo = Wp1 + DD * DD;
#pragma unroll
    for (int ks = 0; ks < 4; ++ks) {
      const float* zp = arow + ks * 32 + grp * 8;
      float4 z0 = *(const float4*)zp, z1 = *(const float4*)(zp + 4);
      bf16x8 ahi, alo; cvt8(z0, z1, &ahi, &alo);
#pragma unroll
      for (int nt = 0; nt < 8; ++nt) {
        size_t off = ((size_t)(nt * 4 + ks) * 64 + l) * 8;
        bf16x8 bhi = *(const bf16x8*)(Whi + off);
        bf16x8 blo = *(const bf16x8*)(Wlo + off);
        acc1[nt] = __builtin_amdgcn_mfma_f32_16x16x32_bf16(ahi, bhi, acc1[nt], 0, 0, 0);
        acc1[nt] = __builtin_amdgcn_mfma_f32_16x16x32_bf16(ahi, blo, acc1[nt], 0, 0, 0);
        acc1[nt] = __builtin_amdgcn_mfma_f32_16x16x32_bf16(alo, bhi, acc1[nt], 0, 0, 0);
      }
    }
  }
  __syncthreads();   // all Z reads complete before H overwrites the tile

  if (active) {
#pragma unroll
    for (int nt = 0; nt < 8; ++nt) {
      float bv = b1[nt * 16 + c];
#pragma unroll
      for (int r = 0; r < 4; ++r)
        my[(grp * 4 + r) * 132 + nt * 16 + c] = fmaxf(acc1[nt][r] + bv, 0.f);
    }
  }
  __syncthreads();

  // ---- phase C: GEMM2 (H @ W2) + bias + residual, write fp32 (+fp16 mirror) ----
  f32x4 acc2[8];
#pragma unroll
  for (int nt = 0; nt < 8; ++nt) acc2[nt] = (f32x4){0.f, 0.f, 0.f, 0.f};
  if (active) {
    const float* arow = my + (l & 15) * 132;
    const unsigned short* Whi = Wp2;
    const unsigned short* Wlo = Wp2 + DD * DD;
#pragma unroll
    for (int ks = 0; ks < 4; ++ks) {
      const float* hp = arow + ks * 32 + grp * 8;
      float4 h0 = *(const float4*)hp, h1 = *(const float4*)(hp + 4);
      bf16x8 ahi, alo; cvt8(h0, h1, &ahi, &alo);
#pragma unroll
      for (int nt = 0; nt < 8; ++nt) {
        size_t off = ((size_t)(nt * 4 + ks) * 64 + l) * 8;
        bf16x8 bhi = *(const bf16x8*)(Whi + off);
        bf16x8 blo = *(const bf16x8*)(Wlo + off);
        acc2[nt] = __builtin_amdgcn_mfma_f32_16x16x32_bf16(ahi, bhi, acc2[nt], 0, 0, 0);
        acc2[nt] = __builtin_amdgcn_mfma_f32_16x16x32_bf16(ahi, blo, acc2[nt], 0, 0, 0);
        acc2[nt] = __builtin_amdgcn_mfma_f32_16x16x32_bf16(alo, bhi, acc2[nt], 0, 0, 0);
      }
    }
#pragma unroll
    for (int nt = 0; nt < 8; ++nt) {
      int col = nt * 16 + c;
      float bv = b2[col];
#pragma unroll
      for (int r = 0; r < 4; ++r) {
        int node = mt * 16 + grp * 4 + r;
        size_t idx = (size_t)node * DD + col;
        float v = acc2[nt][r] + bv + Xf_in[idx];
        Xf_out[idx] = v;
        if (WRITE_H) Xh_out[idx] = (_Float16)v;
      }
    }
  }
}

extern "C" void kernel_launch(void* const* d_in, const int* in_sizes, int n_in,
                              void* d_out, int out_size, void* d_ws, size_t ws_size,
                              hipStream_t stream) {
  const float* X   = (const float*)d_in[0];
  const int*   ei  = (const int*)d_in[1];
  const float* eps = (const float*)d_in[2];
  const float* W1  = (const float*)d_in[3];
  const float* b1  = (const float*)d_in[4];
  const float* W2  = (const float*)d_in[5];
  const float* b2  = (const float*)d_in[6];
  float* Xout = (float*)d_out;

  char* ws = (char*)d_ws;
  size_t off = 0;
  int* cnt = (int*)(ws + off); off += 256 * (((size_t)NN * 4 + 255) / 256);
  int* ell = (int*)(ws + off); off += (size_t)NN * ELLW * 4;
  unsigned short* Wp = (unsigned short*)(ws + off); off += (size_t)6 * 2 * DD * DD * 2;
  _Float16* Xh0 = (_Float16*)(ws + off); off += (size_t)NN * DD * 2;
  _Float16* Xh1 = (_Float16*)(ws + off); off += (size_t)NN * DD * 2;

  hipMemsetAsync(cnt, 0, NN * 4, stream);
  build_ell_k<<<(NE + 255) / 256, 256, 0, stream>>>(ei, cnt, ell);
  pack_w_k<<<(6 * 2048 + 255) / 256, 256, 0, stream>>>(W1, W2, Wp);
  xh_init_k<<<(NN * DD / 8 + 255) / 256, 256, 0, stream>>>(X, Xh0);

  const int fgrid = (MT_TOTAL + 3) / 4;  // 782 blocks x 4 waves
  // layer 0: read input X (fp32) + Xh0, write Xout + Xh1
  fused_layer_k<1><<<fgrid, 256, 0, stream>>>(X, Xh0, cnt, ell, eps, 0,
      Wp + (size_t)0 * 2 * DD * DD, b1 + 0 * DD,
      Wp + (size_t)3 * 2 * DD * DD, b2 + 0 * DD, Xout, Xh1);
  // layer 1: in-place fp32 (block-local rows), Xh1 -> Xh0
  fused_layer_k<1><<<fgrid, 256, 0, stream>>>(Xout, Xh1, cnt, ell, eps, 1,
      Wp + (size_t)1 * 2 * DD * DD, b1 + 1 * DD,
      Wp + (size_t)4 * 2 * DD * DD, b2 + 1 * DD, Xout, Xh0);
  // layer 2: no fp16 mirror needed
  fused_layer_k<0><<<fgrid, 256, 0, stream>>>(Xout, Xh0, cnt, ell, eps, 2,
      Wp + (size_t)2 * 2 * DD * DD, b1 + 2 * DD,
      Wp + (size_t)5 * 2 * DD * DD, b2 + 2 * DD, Xout, nullptr);
}